// Round 4
// baseline (2476.306 us; speedup 1.0000x reference)
//
#include <hip/hip_runtime.h>

// Fully fused quantized encoder, MFMA edition v3b (nontemporal-store fix).
// 512-thread blocks (8 waves), PF=64 frames/pass, FB=256 frames/block.
// GEMMs: bf16 hi/lo 3-term split; A pre-packed frag-stream in d_ws; per-wave
// tile M=32 x N=64; one-kk-ahead A prefetch. Nontemporal output stores.

#define CIN   256
#define LOUT  120000
#define TIN   600000
#define PF    64
#define FB    256
#define NBLK  ((LOUT + FB - 1) / FB)   // 469

typedef float fx4 __attribute__((ext_vector_type(4)));
typedef short bx8 __attribute__((ext_vector_type(8)));

// ---- LDS map ----
#define BF_OFF   0        // 65536: B-frags [kk(8)][nt(4)][hl(2)][1024]
#define CI1_OFF  65536    // 33792: ci1 bf16 [c][66]
#define R2R_OFF  99328    // 18200: r2 ring, 70 slots x 260 B
#define C3R_OFF  117528   // 21320: c3 ring, 82 slots x 260 B
#define XW_OFF   138848   //  1360: x window (340 floats)
#define LDS_SZ   140208

__device__ __forceinline__ float lrelu(float v){ return v >= 0.0f ? v : 0.3f*v; }
__device__ __forceinline__ float clip8(float v){ return fminf(fmaxf(v, -128.0f), 127.0f); }
__device__ __forceinline__ unsigned short f2bf(float f){
  unsigned u = __builtin_bit_cast(unsigned, f);
  return (unsigned short)((u + 0x7FFFu + ((u >> 16) & 1u)) >> 16);  // RNE
}
__device__ __forceinline__ float bf2f(unsigned short h){
  unsigned u = ((unsigned)h) << 16;
  return __builtin_bit_cast(float, u);
}

// GEMM: acc[mt][nt] += A-slice x B-tile, 3-term hi/lo split, A prefetch 1 kk ahead.
// Aw = Apk + mat*262144 + wv*32768 (frag layout: + mt*16384 + kk*2048 + hl*1024 + lane*16)
__device__ __forceinline__ void gemm_mfma(const char* __restrict__ Aw,
                                          const char* __restrict__ Bf,
                                          int lofs, fx4 acc[2][4])
{
  bx8 Ah[2], Al[2];
#pragma unroll
  for (int mt = 0; mt < 2; ++mt) {
    Ah[mt] = *(const bx8*)(Aw + mt*16384 + lofs);
    Al[mt] = *(const bx8*)(Aw + mt*16384 + 1024 + lofs);
  }
#pragma unroll
  for (int kk = 0; kk < 8; ++kk) {
    bx8 Bh[4], Bl[4];
#pragma unroll
    for (int nt = 0; nt < 4; ++nt) {
      Bh[nt] = *(const bx8*)(Bf + kk*8192 + nt*2048 +        lofs);
      Bl[nt] = *(const bx8*)(Bf + kk*8192 + nt*2048 + 1024 + lofs);
    }
    bx8 An[2], Aln[2];
    if (kk < 7) {
#pragma unroll
      for (int mt = 0; mt < 2; ++mt) {
        An[mt]  = *(const bx8*)(Aw + mt*16384 + (kk+1)*2048 +        lofs);
        Aln[mt] = *(const bx8*)(Aw + mt*16384 + (kk+1)*2048 + 1024 + lofs);
      }
    }
#pragma unroll
    for (int mt = 0; mt < 2; ++mt)
#pragma unroll
      for (int nt = 0; nt < 4; ++nt) {
        acc[mt][nt] = __builtin_amdgcn_mfma_f32_16x16x32_bf16(Ah[mt], Bh[nt], acc[mt][nt], 0, 0, 0);
        acc[mt][nt] = __builtin_amdgcn_mfma_f32_16x16x32_bf16(Al[mt], Bh[nt], acc[mt][nt], 0, 0, 0);
        acc[mt][nt] = __builtin_amdgcn_mfma_f32_16x16x32_bf16(Ah[mt], Bl[nt], acc[mt][nt], 0, 0, 0);
      }
#pragma unroll
    for (int mt = 0; mt < 2; ++mt) { Ah[mt] = An[mt]; Al[mt] = Aln[mt]; }
  }
}

// Pack 6 weight matrices [ic][oc] into A-frag stream (hi+lo bf16) in d_ws.
__global__ void pack_w(const float* __restrict__ w0, const float* __restrict__ w1,
                       const float* __restrict__ w2, const float* __restrict__ w3,
                       const float* __restrict__ w4, const float* __restrict__ w5,
                       char* __restrict__ Apk)
{
  const int l = blockIdx.x*256 + threadIdx.x;          // < 49152
  const int lane = l & 63, kk = (l >> 6) & 7, wm = (l >> 9) & 15, mat = l >> 13;
  const float* W = mat==0?w0 : mat==1?w1 : mat==2?w2 : mat==3?w3 : mat==4?w4 : w5;
  const int oc = wm*16 + (lane & 15);
  const int k0 = kk*32 + (lane >> 4)*8;
  unsigned short h[8], lo[8];
#pragma unroll
  for (int j = 0; j < 8; ++j) {
    const float v = W[(k0 + j)*CIN + oc];
    h[j]  = f2bf(v);
    lo[j] = f2bf(v - bf2f(h[j]));
  }
  char* base = Apk + mat*262144 + wm*16384 + kk*2048 + lane*16;
  *(ushort4*)(base)        = make_ushort4(h[0],  h[1],  h[2],  h[3]);
  *(ushort4*)(base + 8)    = make_ushort4(h[4],  h[5],  h[6],  h[7]);
  *(ushort4*)(base + 1024) = make_ushort4(lo[0], lo[1], lo[2], lo[3]);
  *(ushort4*)(base + 1032) = make_ushort4(lo[4], lo[5], lo[6], lo[7]);
}

__launch_bounds__(512, 2)
__global__ void enc_kernel(const float* __restrict__ x,
                           const char* __restrict__ Apk,
                           const float* __restrict__ w_first, const float* __restrict__ b_first,
                           const float* __restrict__ w_dw1, const float* __restrict__ b_dw1,
                           const float* __restrict__ b_pw1, const float* __restrict__ b_lc1,
                           const float* __restrict__ w_dw2, const float* __restrict__ b_dw2,
                           const float* __restrict__ b_pw2, const float* __restrict__ b_lc2,
                           const float* __restrict__ w_dw3, const float* __restrict__ b_dw3,
                           const float* __restrict__ b_pw3, const float* __restrict__ b_lc3,
                           float* __restrict__ out)
{
  __shared__ __align__(16) char lds[LDS_SZ];
  const int tid  = threadIdx.x;
  const int lane = tid & 63;
  const int wv   = tid >> 6;          // 0..7
  const int qq   = lane >> 4;
  const int nn   = lane & 15;
  const int lofs = lane * 16;
  const int t0   = blockIdx.x * FB;
  const fx4 fz = {0.0f, 0.0f, 0.0f, 0.0f};

  const int ch   = tid & 255;         // depthwise channel
  const int half = tid >> 8;          // 0/1 frame-half

  // hoisted per-channel weights (channel = ch)
  float wf[10];
#pragma unroll
  for (int k = 0; k < 10; ++k) wf[k] = w_first[k*CIN + ch];
  const float bfv = b_first[ch];
  const float d10 = w_dw1[ch], d11 = w_dw1[CIN+ch], d12 = w_dw1[2*CIN+ch], bd1 = b_dw1[ch];
  const float d20 = w_dw2[ch], d21 = w_dw2[CIN+ch], d22 = w_dw2[2*CIN+ch], bd2 = b_dw2[ch];
  const float d30 = w_dw3[ch], d31 = w_dw3[CIN+ch], d32 = w_dw3[2*CIN+ch], bd3 = b_dw3[ch];

  // B-frag write base for k-dim = ch
  const int wofs_c = (ch >> 5)*8192 + (((ch & 31) >> 3)*16)*16 + (ch & 7)*2;

  int c0m[2];
#pragma unroll
  for (int mt = 0; mt < 2; ++mt) c0m[mt] = wv*32 + mt*16 + qq*4;

  float resf[2][4][4];
  fx4 acc[2][4];

  for (int pass = 0; pass < 5; ++pass) {
    const int pt0 = t0 - 64 + pass*64;
    const int xbase = 5*pt0 - 15;

    __syncthreads();                       // prev-pass readers done
    if (tid < 340) {
      const int gx = xbase + tid;
      *(float*)&lds[XW_OFF + tid*4] = (gx >= 0 && gx < TIN) ? x[gx] : 0.0f;
    }
    __syncthreads();

    // ---- S1: first conv + leaky -> ci1 bf16, j=0..65 <-> frame pt0+j-2 ----
    for (int jj = 0; jj < 33; ++jj) {
      const int j = half*33 + jj;
      const int t = pt0 + j - 2;
      float a = 0.0f;
#pragma unroll
      for (int k = 0; k < 10; ++k)
        a = fmaf(*(const float*)&lds[XW_OFF + (5*j + k)*4], wf[k], a);
      const float ci = (t < 0) ? 0.0f : lrelu(a + bfv);
      *(unsigned short*)&lds[CI1_OFF + (ch*66 + j)*2] = f2bf(ci);
    }
    __syncthreads();

    // ---- S1b: dw1 (dil 1) -> B-frags (rotation spreads banks) ----
    for (int s = 0; s < 32; ++s) {
      const int j = half*32 + ((s + tid) & 31);
      const float c2 = bf2f(*(const unsigned short*)&lds[CI1_OFF + (ch*66 + j    )*2]);
      const float c1 = bf2f(*(const unsigned short*)&lds[CI1_OFF + (ch*66 + j + 1)*2]);
      const float c0 = bf2f(*(const unsigned short*)&lds[CI1_OFF + (ch*66 + j + 2)*2]);
      const float v = fmaf(d10, c2, fmaf(d11, c1, fmaf(d12, c0, bd1)));
      const int ab = wofs_c + (j >> 4)*2048 + (j & 15)*16;
      const unsigned short hi = f2bf(v);
      *(unsigned short*)&lds[BF_OFF + ab]        = hi;
      *(unsigned short*)&lds[BF_OFF + ab + 1024] = f2bf(v - bf2f(hi));
    }
    __syncthreads();

    // ---- G2: pw1 ----
#pragma unroll
    for (int mt = 0; mt < 2; ++mt)
#pragma unroll
      for (int nt = 0; nt < 4; ++nt) acc[mt][nt] = fz;
    gemm_mfma(Apk + 0*262144 + wv*32768, (const char*)lds + BF_OFF, lofs, acc);
    __syncthreads();
    // E2: +bias, quantize(17.63,-67), leaky -> B-frags
#pragma unroll
    for (int mt = 0; mt < 2; ++mt) {
      const int c0 = c0m[mt];
      const float4 bb = *(const float4*)&b_pw1[c0];
      const float bbv[4] = {bb.x, bb.y, bb.z, bb.w};
      const int ab0 = (c0 >> 5)*8192 + (((c0 & 31) >> 3)*16 + nn)*16 + (c0 & 7)*2;
#pragma unroll
      for (int nt = 0; nt < 4; ++nt) {
        unsigned short h4[4], l4[4];
#pragma unroll
        for (int r = 0; r < 4; ++r) {
          const float h  = acc[mt][nt][r] + bbv[r];
          const float qv = clip8(rintf(h / 17.62967872619629f + 67.0f));
          const float av = lrelu(qv);
          h4[r] = f2bf(av);
          l4[r] = f2bf(av - bf2f(h4[r]));
        }
        const int ab = ab0 + nt*2048;
        *(ushort4*)&lds[BF_OFF + ab]        = make_ushort4(h4[0], h4[1], h4[2], h4[3]);
        *(ushort4*)&lds[BF_OFF + ab + 1024] = make_ushort4(l4[0], l4[1], l4[2], l4[3]);
      }
    }
    __syncthreads();

    // ---- G3: lc1 ----
#pragma unroll
    for (int mt = 0; mt < 2; ++mt)
#pragma unroll
      for (int nt = 0; nt < 4; ++nt) acc[mt][nt] = fz;
    gemm_mfma(Apk + 1*262144 + wv*32768, (const char*)lds + BF_OFF, lofs, acc);
    // E3 (no barrier needed: writes only r2 ring, read after next barrier)
#pragma unroll
    for (int nt = 0; nt < 4; ++nt) {
      const int f = nt*16 + nn;
      const int t = pt0 + f;
      const int slot = (t + 70000) % 70;
#pragma unroll
      for (int mt = 0; mt < 2; ++mt) {
        const int c0 = c0m[mt];
        float r1v[4] = {0.0f, 0.0f, 0.0f, 0.0f};
#pragma unroll
        for (int k = 0; k < 10; ++k) {
          const float xv = *(const float*)&lds[XW_OFF + (5*f + 10 + k)*4];
          const float4 wk = *(const float4*)&w_first[k*CIN + c0];
          r1v[0] = fmaf(xv, wk.x, r1v[0]);
          r1v[1] = fmaf(xv, wk.y, r1v[1]);
          r1v[2] = fmaf(xv, wk.z, r1v[2]);
          r1v[3] = fmaf(xv, wk.w, r1v[3]);
        }
        const float4 bl = *(const float4*)&b_lc1[c0];
        const float4 bf = *(const float4*)&b_first[c0];
        const float blv[4] = {bl.x, bl.y, bl.z, bl.w};
        const float bfa[4] = {bf.x, bf.y, bf.z, bf.w};
        int pk = 0;
#pragma unroll
        for (int r = 0; r < 4; ++r) {
          const float ro1 = (acc[mt][nt][r] + blv[r] - 16.0f) * 6.528060436248779f;
          const float v   = (r1v[r] + bfa[r]) + ro1;
          const float q   = clip8(rintf(v / 12.716455459594727f + 23.0f));
          resf[mt][nt][r] = q;
          pk |= ((int)q & 255) << (8*r);
        }
        *(int*)&lds[R2R_OFF + slot*260 + c0] = pk;
      }
    }
    __syncthreads();

    // ---- S4: dw2 (dil 3) from r2 ring -> B-frags ----
    for (int s = 0; s < 32; ++s) {
      const int j = half*32 + ((s + tid) & 31);
      const int t = pt0 + j;
      float cv[3];
#pragma unroll
      for (int li = 0; li < 3; ++li) {
        const int tt = t - 3*(2 - li);
        float cq;
        if (tt < 0) cq = -47.0f;
        else {
          const int sl = (tt + 70000) % 70;
          const float r = (float)*(const signed char*)&lds[R2R_OFF + sl*260 + ch];
          const float dq = (lrelu(r) + 47.0f) * 5.548006534576416f;
          cq = clip8(rintf(dq / 5.548006534576416f - 47.0f));
        }
        cv[li] = cq;
      }
      const float v = fmaf(d20, cv[0], fmaf(d21, cv[1], fmaf(d22, cv[2], bd2)));
      const int ab = wofs_c + (j >> 4)*2048 + (j & 15)*16;
      const unsigned short hi = f2bf(v);
      *(unsigned short*)&lds[BF_OFF + ab]        = hi;
      *(unsigned short*)&lds[BF_OFF + ab + 1024] = f2bf(v - bf2f(hi));
    }
    __syncthreads();

    // ---- G5: pw2 ----
#pragma unroll
    for (int mt = 0; mt < 2; ++mt)
#pragma unroll
      for (int nt = 0; nt < 4; ++nt) acc[mt][nt] = fz;
    gemm_mfma(Apk + 2*262144 + wv*32768, (const char*)lds + BF_OFF, lofs, acc);
    __syncthreads();
    // E5: +bias, leaky -> B-frags
#pragma unroll
    for (int mt = 0; mt < 2; ++mt) {
      const int c0 = c0m[mt];
      const float4 bb = *(const float4*)&b_pw2[c0];
      const float bbv[4] = {bb.x, bb.y, bb.z, bb.w};
      const int ab0 = (c0 >> 5)*8192 + (((c0 & 31) >> 3)*16 + nn)*16 + (c0 & 7)*2;
#pragma unroll
      for (int nt = 0; nt < 4; ++nt) {
        unsigned short h4[4], l4[4];
#pragma unroll
        for (int r = 0; r < 4; ++r) {
          const float av = lrelu(acc[mt][nt][r] + bbv[r]);
          h4[r] = f2bf(av);
          l4[r] = f2bf(av - bf2f(h4[r]));
        }
        const int ab = ab0 + nt*2048;
        *(ushort4*)&lds[BF_OFF + ab]        = make_ushort4(h4[0], h4[1], h4[2], h4[3]);
        *(ushort4*)&lds[BF_OFF + ab + 1024] = make_ushort4(l4[0], l4[1], l4[2], l4[3]);
      }
    }
    __syncthreads();

    // ---- G6: lc2 ----
#pragma unroll
    for (int mt = 0; mt < 2; ++mt)
#pragma unroll
      for (int nt = 0; nt < 4; ++nt) acc[mt][nt] = fz;
    gemm_mfma(Apk + 3*262144 + wv*32768, (const char*)lds + BF_OFF, lofs, acc);
    // E6: r3 = ro2 + r2 -> resf; ci3 quant -> c3 ring (no barrier before)
#pragma unroll
    for (int nt = 0; nt < 4; ++nt) {
      const int t = pt0 + nt*16 + nn;
      const int slot = (t + 82000) % 82;
#pragma unroll
      for (int mt = 0; mt < 2; ++mt) {
        const int c0 = c0m[mt];
        const float4 bl = *(const float4*)&b_lc2[c0];
        const float blv[4] = {bl.x, bl.y, bl.z, bl.w};
        int pk = 0;
#pragma unroll
        for (int r = 0; r < 4; ++r) {
          const float r3 = (acc[mt][nt][r] + blv[r]) + resf[mt][nt][r];
          resf[mt][nt][r] = r3;
          const float dq = (lrelu(r3) + 38.0f) * 4.458680152893066f;
          const float q  = clip8(rintf(dq / 4.458680152893066f - 38.0f));
          pk |= ((int)q & 255) << (8*r);
        }
        *(int*)&lds[C3R_OFF + slot*260 + c0] = pk;
      }
    }
    __syncthreads();

    if (pass == 0) continue;

    // ---- S7: dw3 (dil 9) from c3 ring -> B-frags ----
    for (int s = 0; s < 32; ++s) {
      const int j = half*32 + ((s + tid) & 31);
      const int t = pt0 + j;
      float cv[3];
#pragma unroll
      for (int li = 0; li < 3; ++li) {
        const int tt = t - 9*(2 - li);
        float cq;
        if (tt < 0) cq = -38.0f;
        else {
          const int sl = (tt + 82000) % 82;
          cq = (float)*(const signed char*)&lds[C3R_OFF + sl*260 + ch];
        }
        cv[li] = cq;
      }
      const float v = fmaf(d30, cv[0], fmaf(d31, cv[1], fmaf(d32, cv[2], bd3)));
      const int ab = wofs_c + (j >> 4)*2048 + (j & 15)*16;
      const unsigned short hi = f2bf(v);
      *(unsigned short*)&lds[BF_OFF + ab]        = hi;
      *(unsigned short*)&lds[BF_OFF + ab + 1024] = f2bf(v - bf2f(hi));
    }
    __syncthreads();

    // ---- G8: pw3 ----
#pragma unroll
    for (int mt = 0; mt < 2; ++mt)
#pragma unroll
      for (int nt = 0; nt < 4; ++nt) acc[mt][nt] = fz;
    gemm_mfma(Apk + 4*262144 + wv*32768, (const char*)lds + BF_OFF, lofs, acc);
    __syncthreads();
    // E8: +bias, leaky -> B-frags
#pragma unroll
    for (int mt = 0; mt < 2; ++mt) {
      const int c0 = c0m[mt];
      const float4 bb = *(const float4*)&b_pw3[c0];
      const float bbv[4] = {bb.x, bb.y, bb.z, bb.w};
      const int ab0 = (c0 >> 5)*8192 + (((c0 & 31) >> 3)*16 + nn)*16 + (c0 & 7)*2;
#pragma unroll
      for (int nt = 0; nt < 4; ++nt) {
        unsigned short h4[4], l4[4];
#pragma unroll
        for (int r = 0; r < 4; ++r) {
          const float av = lrelu(acc[mt][nt][r] + bbv[r]);
          h4[r] = f2bf(av);
          l4[r] = f2bf(av - bf2f(h4[r]));
        }
        const int ab = ab0 + nt*2048;
        *(ushort4*)&lds[BF_OFF + ab]        = make_ushort4(h4[0], h4[1], h4[2], h4[3]);
        *(ushort4*)&lds[BF_OFF + ab + 1024] = make_ushort4(l4[0], l4[1], l4[2], l4[3]);
      }
    }
    __syncthreads();

    // ---- G9: lc3 + final epilogue -> out (nontemporal) ----
#pragma unroll
    for (int mt = 0; mt < 2; ++mt)
#pragma unroll
      for (int nt = 0; nt < 4; ++nt) acc[mt][nt] = fz;
    gemm_mfma(Apk + 5*262144 + wv*32768, (const char*)lds + BF_OFF, lofs, acc);
#pragma unroll
    for (int nt = 0; nt < 4; ++nt) {
      const int t = pt0 + nt*16 + nn;
      if (t < LOUT) {
#pragma unroll
        for (int mt = 0; mt < 2; ++mt) {
          const int c0 = c0m[mt];
          const float4 bl = *(const float4*)&b_lc3[c0];
          const float blv[4] = {bl.x, bl.y, bl.z, bl.w};
          fx4 o;
#pragma unroll
          for (int r = 0; r < 4; ++r) {
            const float r4 = (acc[mt][nt][r] + blv[r]) + resf[mt][nt][r];
            o[r] = (lrelu(r4) + 34.0f) * 3.698859930038452f;
          }
          __builtin_nontemporal_store(o, (fx4*)&out[t*CIN + c0]);
        }
      }
    }
  }
}

extern "C" void kernel_launch(void* const* d_in, const int* in_sizes, int n_in,
                              void* d_out, int out_size, void* d_ws, size_t ws_size,
                              hipStream_t stream) {
  (void)in_sizes; (void)n_in; (void)out_size; (void)ws_size;
  const float* x       = (const float*)d_in[0];
  const float* w_first = (const float*)d_in[5];
  const float* b_first = (const float*)d_in[6];
  const float* w_dw1   = (const float*)d_in[7];
  const float* b_dw1   = (const float*)d_in[8];
  const float* w_pw1   = (const float*)d_in[9];
  const float* b_pw1   = (const float*)d_in[10];
  const float* w_lc1   = (const float*)d_in[11];
  const float* b_lc1   = (const float*)d_in[12];
  const float* w_dw2   = (const float*)d_in[13];
  const float* b_dw2   = (const float*)d_in[14];
  const float* w_pw2   = (const float*)d_in[15];
  const float* b_pw2   = (const float*)d_in[16];
  const float* w_lc2   = (const float*)d_in[17];
  const float* b_lc2   = (const float*)d_in[18];
  const float* w_dw3   = (const float*)d_in[19];
  const float* b_dw3   = (const float*)d_in[20];
  const float* w_pw3   = (const float*)d_in[21];
  const float* b_pw3   = (const float*)d_in[22];
  const float* w_lc3   = (const float*)d_in[23];
  const float* b_lc3   = (const float*)d_in[24];

  char* Apk = (char*)d_ws;                       // 6 x 262144 B = 1.5 MB

  pack_w<<<dim3(192), dim3(256), 0, stream>>>(w_pw1, w_lc1, w_pw2, w_lc2, w_pw3, w_lc3, Apk);
  enc_kernel<<<dim3(NBLK), dim3(512), 0, stream>>>(
      x, Apk, w_first, b_first,
      w_dw1, b_dw1, b_pw1, b_lc1,
      w_dw2, b_dw2, b_pw2, b_lc2,
      w_dw3, b_dw3, b_pw3, b_lc3,
      (float*)d_out);
}